// Round 2
// baseline (257.175 us; speedup 1.0000x reference)
//
#include <hip/hip_runtime.h>

// Multibin binary conv:  y = conv2d(sign(x), sum_m sign(W_m), SAME) + sum_m b_m
// x: [16,256,256,32] f32   W: [4,3,3,32,32] f32   b: [4,32] f32
// out: [16,256,256,32] f32
//
// Implicit GEMM with mfma_i32_32x32x32_i8 (exact: signs ±1 i8, wsum {-4..4} i8,
// i32 accumulate, cvt f32 at store).
// 1-wave workgroups (64 thr): 32-col x 8-row strip, rolling 4-slot LDS row
// buffer, NO __syncthreads (intra-wave DS ordering).  Grid 4096 = 16 blk/CU.
//
// Round-2 change: DEPTH-2 register prefetch.  Loads for row r+3 issued at
// iter i; row r+2 (loaded at iter i-1) committed to LDS at end of iter i.
// The vmcnt wait before each LDS commit targets loads issued one full
// iteration earlier (oldest in queue -> counted wait, not blocked by the
// younger nontemporal stores).  Prologue rows issued as one burst, then
// committed in order (counted waits overlap the 3 row latencies).

#define RH      8
#define NSTAGE  34                  // 32 cols + 2 halo
#define PITCHB  48                  // bytes per pixel (32 ci + 16 pad)
#define SLOTB   (NSTAGE * PITCHB)   // 1632 B per slot; 4 slots = 6528 B

typedef __attribute__((ext_vector_type(4)))  int i32x4;
typedef __attribute__((ext_vector_type(16))) int i32x16;

__device__ __forceinline__ unsigned int pack4(float4 v, bool ok) {
    // sign(x) as i8: +1 = 0x01, -1 = 0xFF; padding -> 0
    if (!ok) return 0u;
    unsigned r = (v.x >= 0.0f) ? 0x01u : 0xFFu;
    r |= ((v.y >= 0.0f) ? 0x01u : 0xFFu) << 8;
    r |= ((v.z >= 0.0f) ? 0x01u : 0xFFu) << 16;
    r |= ((v.w >= 0.0f) ? 0x01u : 0xFFu) << 24;
    return r;
}

// ---------------- prep: wsT[co][288] i8 + bsum[32] f32 into d_ws ----------------
__global__ void prep_kernel(const float* __restrict__ W, const float* __restrict__ bias,
                            signed char* __restrict__ wsT, float* __restrict__ bsum) {
    int t = blockIdx.x * 256 + threadIdx.x;
    if (t < 9216) {
        int k   = t >> 5;          // 0..287 = tap*32 + ci
        int co  = t & 31;
        int tap = k >> 5;          // dh*3+dw
        int ci  = k & 31;
        float s = 0.0f;
        #pragma unroll
        for (int m = 0; m < 4; ++m) {
            float w = W[(m * 9 + tap) * 1024 + ci * 32 + co];
            s += (w >= 0.0f) ? 1.0f : -1.0f;
        }
        wsT[co * 288 + k] = (signed char)(int)s;   // exact, in {-4..4}
    }
    if (t < 32) {
        float s = 0.0f;
        #pragma unroll
        for (int m = 0; m < 4; ++m) s += bias[m * 32 + t];
        bsum[t] = s;
    }
}

// issue global loads of one image row into named register buffers (static idx)
#define ISSUE(ABSROW, V0, V1)                                                   \
    do {                                                                        \
        const int absrow_ = (ABSROW);                                           \
        const bool rowok_ = (absrow_ >= 0) && (absrow_ < 256);                  \
        const float* rowp_ = x + (long)((bimg * 256 + absrow_) * 256) * 32;     \
        _Pragma("unroll")                                                       \
        for (int p = 0; p < 3; ++p) {                                           \
            bool ok = rowok_ && cok[p];                                         \
            const float4* pp = (const float4*)(rowp_ + ldoff[p]);               \
            V0[p] = ok ? pp[0] : make_float4(0.f, 0.f, 0.f, 0.f);               \
            V1[p] = ok ? pp[1] : make_float4(0.f, 0.f, 0.f, 0.f);               \
        }                                                                       \
    } while (0)

// pack + LDS-write a previously issued row into slot SL
#define COMMIT(ABSROW, SL, V0, V1)                                              \
    do {                                                                        \
        const int absrow_ = (ABSROW);                                           \
        const bool rowok_ = (absrow_ >= 0) && (absrow_ < 256);                  \
        unsigned char* dst_ = lds + (SL) * SLOTB;                               \
        _Pragma("unroll")                                                       \
        for (int p = 0; p < 3; ++p) {                                           \
            if (pvalid[p]) {                                                    \
                bool ok = rowok_ && cok[p];                                     \
                *(uint2*)(dst_ + pix[p] * PITCHB + ch[p] * 8) =                 \
                    make_uint2(pack4(V0[p], ok), pack4(V1[p], ok));             \
            }                                                                   \
        }                                                                       \
    } while (0)

__global__ __launch_bounds__(64, 4) void conv_kernel(const float* __restrict__ x,
                                                     const signed char* __restrict__ wsT,
                                                     const float* __restrict__ bsum,
                                                     float* __restrict__ out) {
    __shared__ __align__(16) unsigned char lds[4 * SLOTB];

    const int lane = threadIdx.x;     // single wave per block
    const int lrow = lane & 31;       // A: pixel row / B,D: cout column
    const int lk   = lane >> 5;       // K-half selector

    const int bs   = blockIdx.x;      // 4096 = 16 img x 32 rowstrips x 8 colstrips
    const int c0   = (bs & 7) * 32;
    const int r0   = ((bs >> 3) & 31) * RH;
    const int bimg = bs >> 8;

    // fixed per-thread load geometry (34 px x 4 chunks of 8 floats, 136 units)
    int pix[3], ch[3]; bool pvalid[3], cok[3]; long ldoff[3];
    #pragma unroll
    for (int p = 0; p < 3; ++p) {
        int f = lane + p * 64;
        pix[p] = f >> 2; ch[p] = f & 3;
        pvalid[p] = (pix[p] < NSTAGE);
        int col = c0 - 1 + pix[p];
        cok[p] = pvalid[p] && (col >= 0) && (col < 256);
        ldoff[p] = (long)col * 32 + ch[p] * 8;
    }

    // ---- prologue: burst-issue 3 halo/first rows, then commit in order ----
    float4 pa0[3], pa1[3], pb0[3], pb1[3], pc0[3], pc1[3];
    ISSUE(r0 - 1, pa0, pa1);
    ISSUE(r0,     pb0, pb1);
    ISSUE(r0 + 1, pc0, pc1);
    COMMIT(r0 - 1, 0, pa0, pa1);
    COMMIT(r0,     1, pb0, pb1);
    COMMIT(r0 + 1, 2, pc0, pc1);

    // B fragments (L2-hot; load after the global burst):
    // lane holds B[k = lk*16 + j][n = lrow] = wsT[lrow][tap*32 + lk*16 + j]
    i32x4 bfrag[9];
    #pragma unroll
    for (int t = 0; t < 9; ++t)
        bfrag[t] = *(const i32x4*)(wsT + lrow * 288 + t * 32 + lk * 16);
    const float bsv = bsum[lrow];

    // depth-2 pipeline: buf[i&1] holds row r0+i+2 at top of iter i
    float4 b0[2][3], b1[2][3];
    ISSUE(r0 + 2, b0[0], b1[0]);

    const int a_off = lrow * PITCHB + lk * 16;

    #pragma unroll
    for (int i = 0; i < RH; ++i) {
        const int cur = i & 1, nxt = cur ^ 1;   // compile-time under full unroll

        // issue loads for row r0+i+3 (consumed at iter i+1's commit)
        if (i <= RH - 3) ISSUE(r0 + i + 3, b0[nxt], b1[nxt]);

        // ---- compute output row r0+i from slots (i, i+1, i+2) & 3 ----
        i32x16 acc = {};
        #pragma unroll
        for (int dh = 0; dh < 3; ++dh) {
            const unsigned char* sb = lds + ((i + dh) & 3) * SLOTB + a_off;
            #pragma unroll
            for (int dw = 0; dw < 3; ++dw) {
                i32x4 a = *(const i32x4*)(sb + dw * PITCHB);
                acc = __builtin_amdgcn_mfma_i32_32x32x32_i8(a, bfrag[dh * 3 + dw],
                                                            acc, 0, 0, 0);
            }
        }

        // ---- store: D col = lrow (cout), row = (reg&3)+8*(reg>>2)+4*lk ----
        float* op = out + ((long)((bimg * 256 + (r0 + i)) * 256 + c0)) * 32 + lrow;
        #pragma unroll
        for (int reg = 0; reg < 16; ++reg) {
            int pr = (reg & 3) + 8 * (reg >> 2) + 4 * lk;
            __builtin_nontemporal_store((float)acc[reg] + bsv, op + pr * 32);
        }

        // ---- commit row r0+i+2 (loaded at iter i-1 / prologue) into LDS ----
        if (i <= RH - 2) COMMIT(r0 + i + 2, (i + 3) & 3, b0[cur], b1[cur]);
    }
}

extern "C" void kernel_launch(void* const* d_in, const int* in_sizes, int n_in,
                              void* d_out, int out_size, void* d_ws, size_t ws_size,
                              hipStream_t stream) {
    const float* x    = (const float*)d_in[0];   // [16,256,256,32]
    const float* W    = (const float*)d_in[1];   // [4,3,3,32,32]
    const float* bias = (const float*)d_in[2];   // [4,32]
    float* out = (float*)d_out;

    signed char* wsT = (signed char*)d_ws;              // 9216 B
    float* bsum = (float*)((char*)d_ws + 9216);         // 32 f32

    prep_kernel<<<36, 256, 0, stream>>>(W, bias, wsT, bsum);
    conv_kernel<<<4096, 64, 0, stream>>>(x, wsT, bsum, out);
}

// Round 3
// 246.789 us; speedup vs baseline: 1.0421x; 1.0421x over previous
//
#include <hip/hip_runtime.h>

// Multibin binary conv:  y = conv2d(sign(x), sum_m sign(W_m), SAME) + sum_m b_m
// x: [16,256,256,32] f32   W: [4,3,3,32,32] f32   b: [4,32] f32 -> out f32
//
// Implicit GEMM, mfma_i32_32x32x32_i8 (exact: signs ±1 i8, wsum {-4..4} i8).
// 1-wave blocks (64 thr), 32-col x 8-row strip, grid 4096.  NO barriers.
//
// Round-3: rows staged ASYNC via global_load_lds (raw f32, ring of 3 LDS
// slots, zero VGPR in-flight cost), then packed LDS->LDS to the i8 im2col
// buffer (ring of 4).  Depth-2 pipeline with counted vmcnt waits: the wait
// for row r+2's DMA allows the 16 output stores + row r+3's loads to stay
// outstanding (never drains the queue).  Halo px handled by one per-lane
// dword load issued last per row & consumed first in pack, so the
// compiler's own dependency wait subsumes the manual ledger (spill-proof).
// Raw-slot XOR word swizzle (applied on the GLOBAL source address; DMA is
// lane-linear on the LDS side) makes the pack ds_read_b128 conflict-free.

#define RH      8
#define PITCHB  48                    // packed bytes per pixel (32 ci + 16 pad)
#define PSLOT   (34 * PITCHB)         // 1632 B packed row slot (x4)
#define RSLOT   4096                  // raw slot: 32 interior px * 128 B (x3)
#define RAWOFF  (4 * PSLOT)           // packed [0,6528) raw [6528,18816)

typedef __attribute__((ext_vector_type(4)))  int i32x4;
typedef __attribute__((ext_vector_type(16))) int i32x16;

__device__ __forceinline__ void gload16(const void* g, void* l) {
    __builtin_amdgcn_global_load_lds(
        (const __attribute__((address_space(1))) void*)g,
        (__attribute__((address_space(3))) void*)l, 16, 0, 0);
}

__device__ __forceinline__ unsigned packsgn4(uint4 v) {
    unsigned r;
    r  =  (__uint_as_float(v.x) >= 0.0f) ? 0x01u : 0xFFu;
    r |= ((__uint_as_float(v.y) >= 0.0f) ? 0x01u : 0xFFu) << 8;
    r |= ((__uint_as_float(v.z) >= 0.0f) ? 0x01u : 0xFFu) << 16;
    r |= ((__uint_as_float(v.w) >= 0.0f) ? 0x01u : 0xFFu) << 24;
    return r;
}

// ---------------- prep: wsT[co][288] i8 + bsum[32] f32 into d_ws ----------------
__global__ void prep_kernel(const float* __restrict__ W, const float* __restrict__ bias,
                            signed char* __restrict__ wsT, float* __restrict__ bsum) {
    int t = blockIdx.x * 256 + threadIdx.x;
    if (t < 9216) {
        int k   = t >> 5;          // 0..287 = tap*32 + ci
        int co  = t & 31;
        int tap = k >> 5;
        int ci  = k & 31;
        float s = 0.0f;
        #pragma unroll
        for (int m = 0; m < 4; ++m) {
            float w = W[(m * 9 + tap) * 1024 + ci * 32 + co];
            s += (w >= 0.0f) ? 1.0f : -1.0f;
        }
        wsT[co * 288 + k] = (signed char)(int)s;
    }
    if (t < 32) {
        float s = 0.0f;
        #pragma unroll
        for (int m = 0; m < 4; ++m) s += bias[m * 32 + t];
        bsum[t] = s;
    }
}

// counted wait + scheduling fence
#define WAITV(N)                                                                \
    do {                                                                        \
        asm volatile("s_waitcnt vmcnt(" #N ")" ::: "memory");                   \
        __builtin_amdgcn_sched_barrier(0);                                      \
    } while (0)

// halo register select by row index (ring of 3, compile-time)
#define HSEL(J) ((((J) % 3) == 0) ? h0 : ((((J) % 3) == 1) ? h1 : h2))

// issue one row's staging: 4x global_load_lds (interior, swizzled source) +
// 1 per-lane halo dword (issued LAST -> its auto-wait covers the DMA too).
// 5 VMEM ops exactly.  sched_barrier pins the group in program order.
#define ISSUE_ROW(J, HREG)                                                      \
    do {                                                                        \
        const int row_  = r0 - 1 + (J);                                         \
        const int rowc_ = row_ < 0 ? 0 : (row_ > 255 ? 255 : row_);             \
        const char* gb_ = (const char*)(x + (long)((bimg * 256 + rowc_) * 256   \
                                                   + c0) * 32);                 \
        unsigned char* lb_ = lds + RAWOFF + ((J) % 3) * RSLOT;                  \
        _Pragma("unroll")                                                       \
        for (int k_ = 0; k_ < 4; ++k_)                                          \
            gload16(gb_ + k_ * 1024 + lswz16, lb_ + k_ * 1024);                 \
        HREG = *(x + (long)(bimg * 256 + rowc_) * 8192 + hoff);                 \
        __builtin_amdgcn_sched_barrier(0);                                      \
    } while (0)

// pack row J (raw f32 LDS -> signed i8 im2col LDS).  Halo byte FIRST
// (forces compiler's counted vmcnt for HREG, which retires the older DMA).
#define PACK_ROW(J, HREG)                                                       \
    do {                                                                        \
        const int row_   = r0 - 1 + (J);                                        \
        const bool rowok_ = (row_ >= 0) && (row_ < 256);                        \
        unsigned char* ps_ = lds + ((J) & 3) * PSLOT;                           \
        const unsigned char* rs_ = lds + RAWOFF + ((J) % 3) * RSLOT;            \
        ps_[hpx * PITCHB + (lane & 31)] =                                       \
            (rowok_ && hok) ? ((HREG >= 0.0f) ? 0x01 : 0xFF) : 0;               \
        uint4 o_;                                                               \
        if (rowok_) {                                                           \
            uint4 w0_ = *(const uint4*)(rs_ + (ppx * 8 + ((ph * 4 + 0) ^ pxr)) * 16); \
            uint4 w1_ = *(const uint4*)(rs_ + (ppx * 8 + ((ph * 4 + 1) ^ pxr)) * 16); \
            uint4 w2_ = *(const uint4*)(rs_ + (ppx * 8 + ((ph * 4 + 2) ^ pxr)) * 16); \
            uint4 w3_ = *(const uint4*)(rs_ + (ppx * 8 + ((ph * 4 + 3) ^ pxr)) * 16); \
            o_ = make_uint4(packsgn4(w0_), packsgn4(w1_),                       \
                            packsgn4(w2_), packsgn4(w3_));                      \
        } else {                                                                \
            o_ = make_uint4(0u, 0u, 0u, 0u);                                    \
        }                                                                       \
        *(uint4*)(ps_ + (ppx + 1) * PITCHB + ph * 16) = o_;                     \
    } while (0)

__global__ __launch_bounds__(64, 2) void conv_kernel(const float* __restrict__ x,
                                                     const signed char* __restrict__ wsT,
                                                     const float* __restrict__ bsum,
                                                     float* __restrict__ out) {
    __shared__ __align__(16) unsigned char lds[4 * PSLOT + 3 * RSLOT];  // 18816 B

    const int lane = threadIdx.x;     // single wave per block
    const int lrow = lane & 31;       // A: pixel row / B,D: cout column
    const int lk   = lane >> 5;       // K-half selector

    const int bs   = blockIdx.x;      // 4096 = 16 img x 32 rowstrips x 8 colstrips
    const int c0   = (bs & 7) * 32;
    const int r0   = ((bs >> 3) & 31) * RH;
    const int bimg = bs >> 8;

    // B fragments + bias first: their 10 VMEM ops retire under prologue waits
    i32x4 bfrag[9];
    #pragma unroll
    for (int t = 0; t < 9; ++t)
        bfrag[t] = *(const i32x4*)(wsT + lrow * 288 + t * 32 + lk * 16);
    const float bsv = bsum[lrow];

    // geometry
    const int lswz16 = (lane ^ ((lane >> 3) & 7)) * 16;   // global-side pre-swizzle
    const int hcol   = (lane < 32) ? (c0 > 0 ? c0 - 1 : 0)
                                   : (c0 + 32 < 256 ? c0 + 32 : 255);
    const bool hok   = (lane < 32) ? (c0 > 0) : (c0 + 32 < 256);
    const int  hpx   = (lane < 32) ? 0 : 33;
    const long hoff  = (long)hcol * 32 + (lane & 31);     // in floats
    const int  ppx   = lane >> 1;                         // pack: pixel 0..31
    const int  ph    = lane & 1;                          // pack: ci half
    const int  pxr   = ppx & 7;                           // raw read de-swizzle

    float h0 = 0.f, h1 = 0.f, h2 = 0.f;

    // ---- prologue: rows j0..j2 async, packed under counted waits ----
    ISSUE_ROW(0, HSEL(0));
    ISSUE_ROW(1, HSEL(1));
    ISSUE_ROW(2, HSEL(2));
    WAITV(10);  PACK_ROW(0, HSEL(0));
    WAITV(5);   PACK_ROW(1, HSEL(1));
    ISSUE_ROW(3, HSEL(3));
    WAITV(5);   PACK_ROW(2, HSEL(2));

    const int a_off = lrow * PITCHB + lk * 16;

    #pragma unroll
    for (int i = 0; i < RH; ++i) {
        // issue row j=i+4 (rows j0..j9 total)
        if (i <= RH - 3) ISSUE_ROW(i + 4, HSEL(i + 4));

        // wait for row j=i+3's DMA (one full iteration old); stores + fresh
        // loads stay outstanding.  Ledger (group order pinned by sched_barriers):
        //   i=0: [j4:5] -> 5    i=1..5: [stores:16][j:5] -> 21    i=6: [stores:16] -> 16
        if (i == 0)      { WAITV(5);  }
        else if (i == 1) { WAITV(21); }
        else if (i == 2) { WAITV(21); }
        else if (i == 3) { WAITV(21); }
        else if (i == 4) { WAITV(21); }
        else if (i == 5) { WAITV(21); }
        else if (i == 6) { WAITV(16); }
        if (i <= RH - 2) PACK_ROW(i + 3, HSEL(i + 3));

        // ---- MFMA: output row r0+i from packed slots (i, i+1, i+2) & 3 ----
        i32x16 acc = {};
        #pragma unroll
        for (int dh = 0; dh < 3; ++dh) {
            const unsigned char* sb = lds + ((i + dh) & 3) * PSLOT + a_off;
            #pragma unroll
            for (int dw = 0; dw < 3; ++dw) {
                i32x4 a = *(const i32x4*)(sb + dw * PITCHB);
                acc = __builtin_amdgcn_mfma_i32_32x32x32_i8(a, bfrag[dh * 3 + dw],
                                                            acc, 0, 0, 0);
            }
        }

        // ---- store: D col = lrow (cout), row = (reg&3)+8*(reg>>2)+4*lk ----
        float* op = out + ((long)((bimg * 256 + (r0 + i)) * 256 + c0)) * 32 + lrow;
        #pragma unroll
        for (int reg = 0; reg < 16; ++reg) {
            int pr = (reg & 3) + 8 * (reg >> 2) + 4 * lk;
            __builtin_nontemporal_store((float)acc[reg] + bsv, op + pr * 32);
        }
    }
}

extern "C" void kernel_launch(void* const* d_in, const int* in_sizes, int n_in,
                              void* d_out, int out_size, void* d_ws, size_t ws_size,
                              hipStream_t stream) {
    const float* x    = (const float*)d_in[0];   // [16,256,256,32]
    const float* W    = (const float*)d_in[1];   // [4,3,3,32,32]
    const float* bias = (const float*)d_in[2];   // [4,32]
    float* out = (float*)d_out;

    signed char* wsT = (signed char*)d_ws;              // 9216 B
    float* bsum = (float*)((char*)d_ws + 9216);         // 32 f32

    prep_kernel<<<36, 256, 0, stream>>>(W, bias, wsT, bsum);
    conv_kernel<<<4096, 64, 0, stream>>>(x, wsT, bsum, out);
}